// Round 7
// baseline (375.787 us; speedup 1.0000x reference)
//
#include <hip/hip_runtime.h>
#include <hip/hip_bf16.h>

// GRU-like fused cell: out = (1-z)*tanh(i_n + r*h_n) + z*e
// B=8, H=512, N=8192. bf16 MFMA 16x16x32, fp32 acc, fused epilogue.
//
// R6 -> R7: __syncthreads() = s_waitcnt vmcnt(0) -- it drained the fresh
// A(s+1)/X(s+3) prefetches every step, serializing each WG into a
// latency chain (T4 violation). Replace with counted-vmcnt raw barrier:
// issue order [A gloads(6), X loads(8)], barrier waits vmcnt(8) lgkmcnt(0)
// => A complete, X stays in flight across the barrier (~1300 cyc cover).

#define HH 512
#define NBATCH 8
#define NN 8192
#define BN 128
#define BK 64
#define NSTEPS 16
#define THREADS 256
#define A_BYTES (192 * BK * 2)          // 24576
#define B_BYTES (BN * BK * 2)           // 16384
#define BUF_BYTES (A_BYTES + B_BYTES)   // 40960
#define LDS_TOTAL (2 * BUF_BYTES)       // 81920 -> 2 WGs/CU

typedef __attribute__((ext_vector_type(8))) short short8;
typedef __attribute__((ext_vector_type(4))) float f32x4;

__device__ __forceinline__ unsigned cvt_pk_bf16(float a, float b) {
  unsigned r;
  asm("v_cvt_pk_bf16_f32 %0, %1, %2" : "=v"(r) : "v"(a), "v"(b));
  return r;
}

__device__ __forceinline__ void gload_lds16(const void* g, void* l) {
  __builtin_amdgcn_global_load_lds(
      (__attribute__((address_space(1))) void*)(g),
      (__attribute__((address_space(3))) void*)(l), 16, 0, 0);
}

#define MFMA16(a_, b_, c_) __builtin_amdgcn_mfma_f32_16x16x32_bf16((a_), (b_), (c_), 0, 0, 0)

// ---------------- weight pre-pack (unchanged, verified R1-R6) ----------------
__global__ void prepack_w(const float* __restrict__ W_ih, const float* __restrict__ W_hh,
                          __hip_bfloat16* __restrict__ ws) {
  int t = blockIdx.x * 256 + threadIdx.x;
  int blk = t / 12288;                              // ht*16 + s
  int e = t % 12288;
  int ra = e >> 6;                                  // 0..191
  int kk = (e & 63) ^ ((ra & 7) << 3);              // inverse of read-side XOR swizzle
  int gate = ra >> 6;
  int h = (blk >> 4) * 64 + (ra & 63);
  int row = gate * HH + h;
  int kg = (blk & 15) * 64 + kk;
  float v = (kg < 512) ? W_ih[row * 512 + kg] : W_hh[row * 512 + (kg - 512)];
  ws[t] = __float2bfloat16(v);
}

// ---------------- main fused kernel ----------------
__global__ __launch_bounds__(THREADS, 2)
void gru_main(const float* __restrict__ e_wv, const float* __restrict__ m_wv,
              const __hip_bfloat16* __restrict__ wimg, float* __restrict__ out) {
  extern __shared__ char smem[];
  const int tid  = threadIdx.x;
  const int lane = tid & 63;
  const int wave = tid >> 6;       // 0..3
  const int wm = wave >> 1;        // 0..1 : 32-row half of 64-h tile
  const int wn = wave & 1;         // 0..1 : 64-col half of 128-n tile

  // XCD swizzle (bijective: 4096 % 8 == 0), ht fastest.
  const int wg  = blockIdx.x;
  const int swz = (wg & 7) * 512 + (wg >> 3);
  const int ht  = swz & 7;
  const int nt  = (swz >> 3) & 63;
  const int b   = swz >> 9;

  const int k0  = (tid & 15) << 2;   // 0..60  (4 k-rows per thread)
  const int n0s = (tid >> 4) << 3;   // 0..120 (8 n-cols per thread)

  const size_t batch_off = (size_t)b * HH * NN;
  const float* xm = m_wv + batch_off + (size_t)k0 * NN + nt * BN + n0s;
  const float* xe = e_wv + batch_off + (size_t)k0 * NN + nt * BN + n0s;
  const char*  wA = (const char*)wimg + (size_t)ht * NSTEPS * A_BYTES + tid * 16;

  f32x4 acc_r[2][4]  = {};
  f32x4 acc_z[2][4]  = {};
  f32x4 acc_in[2][4] = {};
  f32x4 acc_hn[2][4] = {};

  f32x4 cA[4], cB[4];   // transient f32 X (32 regs): X(s+2)-in-flight / X(s+3) after issue
  uint2 pk[8];          // packed bf16 X(s+1) (16 regs), crosses barrier

  int aoff[2], boff[2];
#pragma unroll
  for (int kb2 = 0; kb2 < 2; ++kb2) {
    const int ke2 = kb2 * 64 + ((lane >> 4) << 4);
    const int sw  = (lane & 7) << 4;
    aoff[kb2] = (wm * 32 + (lane & 15)) * 128 + (ke2 ^ sw);
    boff[kb2] = A_BYTES + (wn * 64 + (lane & 15)) * 128 + (ke2 ^ sw);
  }

  auto issue_A = [&](int s, char* nb) {
    const char* gA = wA + (size_t)s * A_BYTES;
    char* lA = nb + tid * 16;
#pragma unroll
    for (int i = 0; i < 6; ++i)
      gload_lds16(gA + i * 4096, lA + i * 4096);
  };
  auto x_load = [&](const float* xs) {
#pragma unroll
    for (int i = 0; i < 4; ++i) {
      cA[i] = *(const f32x4*)(xs + (size_t)i * NN);
      cB[i] = *(const f32x4*)(xs + (size_t)i * NN + 4);
    }
  };
  auto x_cvt = [&]() {   // f32 -> packed bf16; vm wait lands here (loads are a full step old)
#pragma unroll
    for (int j = 0; j < 4; ++j) {
      pk[j]     = make_uint2(cvt_pk_bf16(cA[0][j], cA[1][j]),
                             cvt_pk_bf16(cA[2][j], cA[3][j]));
      pk[j + 4] = make_uint2(cvt_pk_bf16(cB[0][j], cB[1][j]),
                             cvt_pk_bf16(cB[2][j], cB[3][j]));
    }
  };
  auto write_X = [&](char* nb) {   // pure LDS, no vm dependency
    char* Bb = nb + A_BYTES;
#pragma unroll
    for (int j = 0; j < 8; ++j) {
      int off = (n0s + j) * 128 + ((k0 * 2) ^ (j << 4));   // (n&7)==j
      *(uint2*)(Bb + off) = pk[j];
    }
  };
  auto compute_kb2 = [&](const char* cb, int kb2, bool firstHalf) {
    short8 bfr[4];
#pragma unroll
    for (int ni = 0; ni < 4; ++ni)
      bfr[ni] = *(const short8*)(cb + boff[kb2] + ni * 2048);
    {  // gate r
      short8 a0 = *(const short8*)(cb + aoff[kb2]);
      short8 a1 = *(const short8*)(cb + aoff[kb2] + 2048);
#pragma unroll
      for (int ni = 0; ni < 4; ++ni) {
        acc_r[0][ni] = MFMA16(a0, bfr[ni], acc_r[0][ni]);
        acc_r[1][ni] = MFMA16(a1, bfr[ni], acc_r[1][ni]);
      }
    }
    {  // gate z
      short8 a0 = *(const short8*)(cb + aoff[kb2] + 8192);
      short8 a1 = *(const short8*)(cb + aoff[kb2] + 8192 + 2048);
#pragma unroll
      for (int ni = 0; ni < 4; ++ni) {
        acc_z[0][ni] = MFMA16(a0, bfr[ni], acc_z[0][ni]);
        acc_z[1][ni] = MFMA16(a1, bfr[ni], acc_z[1][ni]);
      }
    }
    {  // gate n -> acc_in (m-phase) / acc_hn (e-phase)
      short8 a0 = *(const short8*)(cb + aoff[kb2] + 16384);
      short8 a1 = *(const short8*)(cb + aoff[kb2] + 16384 + 2048);
      if (firstHalf) {
#pragma unroll
        for (int ni = 0; ni < 4; ++ni) {
          acc_in[0][ni] = MFMA16(a0, bfr[ni], acc_in[0][ni]);
          acc_in[1][ni] = MFMA16(a1, bfr[ni], acc_in[1][ni]);
        }
      } else {
#pragma unroll
        for (int ni = 0; ni < 4; ++ni) {
          acc_hn[0][ni] = MFMA16(a0, bfr[ni], acc_hn[0][ni]);
          acc_hn[1][ni] = MFMA16(a1, bfr[ni], acc_hn[1][ni]);
        }
      }
    }
  };

  // prologue: buf0 <- {A(0), X(0)}; pk = X(1); X(2) in flight
  issue_A(0, smem);                       // 6 vm (oldest)
  x_load(xm);                             // X(0)
  x_cvt();                                // drains A(0)+X(0); pk = X(0)
  write_X(smem);
  x_load(xm + (size_t)(64 * NN));         // X(1)
  x_cvt();                                // pk = X(1)
  x_load(xm + (size_t)(2 * 64 * NN));     // X(2): stays in flight
  asm volatile("s_waitcnt vmcnt(8) lgkmcnt(0)" ::: "memory");
  __builtin_amdgcn_sched_barrier(0);
  __builtin_amdgcn_s_barrier();
  __builtin_amdgcn_sched_barrier(0);

#pragma unroll 1
  for (int s = 0; s < NSTEPS; ++s) {
    char* cb = smem + ((s & 1) ? BUF_BYTES : 0);
    char* nb = smem + ((s & 1) ? 0 : BUF_BYTES);
    const bool firstHalf = (s < 8);

    if (s + 1 < NSTEPS) write_X(nb);      // pk = X(s+1) -> LDS (pure ds_write)
    if (s + 2 < NSTEPS) x_cvt();          // pk <- X(s+2); loads are one full step old
    if (s + 1 < NSTEPS) issue_A(s + 1, nb);            // 6 gloads (L2-hot weights)
    if (s + 3 < NSTEPS) {
      const int t = s + 3;
      x_load((t < 8 ? xm : xe) + (size_t)(t & 7) * (64 * NN));   // 8 vm, newest
    }

    __builtin_amdgcn_s_setprio(1);
    compute_kb2(cb, 0, firstHalf);
    compute_kb2(cb, 1, firstHalf);
    __builtin_amdgcn_s_setprio(0);

    if (s < NSTEPS - 1) {
      // A(s+1) complete (issued before the 8 X loads); X(s+3) stays in flight.
      if (s + 3 < NSTEPS) {
        asm volatile("s_waitcnt vmcnt(8) lgkmcnt(0)" ::: "memory");
      } else {
        asm volatile("s_waitcnt vmcnt(0) lgkmcnt(0)" ::: "memory");
      }
      __builtin_amdgcn_sched_barrier(0);
      __builtin_amdgcn_s_barrier();
      __builtin_amdgcn_sched_barrier(0);
    }
  }

  // epilogue: gates + blend (unchanged, verified R1-R6)
  const size_t obase = batch_off + (size_t)(ht * 64 + wm * 32) * NN + nt * BN + wn * 64;
  const float* ep = e_wv + obase;
  float* op = out + obase;
  const int rsub = (lane >> 4) << 2;
  const int csub = lane & 15;
#pragma unroll
  for (int mi = 0; mi < 2; ++mi)
#pragma unroll
    for (int ni = 0; ni < 4; ++ni) {
#pragma unroll
      for (int r = 0; r < 4; ++r) {
        size_t idx = (size_t)(mi * 16 + rsub + r) * NN + ni * 16 + csub;
        float pr  = acc_r[mi][ni][r];
        float pz  = acc_z[mi][ni][r];
        float vin = acc_in[mi][ni][r];
        float vhn = acc_hn[mi][ni][r];
        float rr  = 1.f / (1.f + __expf(-pr));
        float zz  = 1.f / (1.f + __expf(-pz));
        float ex  = __expf(2.f * (vin + rr * vhn));
        float nn2 = 1.f - 2.f / (ex + 1.f);      // tanh, inf-safe
        float ev  = ep[idx];
        op[idx] = (1.f - zz) * nn2 + zz * ev;
      }
    }
}

extern "C" void kernel_launch(void* const* d_in, const int* in_sizes, int n_in,
                              void* d_out, int out_size, void* d_ws, size_t ws_size,
                              hipStream_t stream) {
  const float* e_wv = (const float*)d_in[0];
  const float* m_wv = (const float*)d_in[1];
  const float* W_ih = (const float*)d_in[2];
  const float* W_hh = (const float*)d_in[3];
  float* out = (float*)d_out;
  __hip_bfloat16* wimg = (__hip_bfloat16*)d_ws;   // 3 MiB weight image

  (void)hipFuncSetAttribute((const void*)gru_main,
                            hipFuncAttributeMaxDynamicSharedMemorySize, LDS_TOTAL);

  prepack_w<<<(NBATCH * NSTEPS * 12288) / 256, 256, 0, stream>>>(W_ih, W_hh, wimg);
  gru_main<<<NBATCH * 8 * 64, THREADS, LDS_TOTAL, stream>>>(e_wv, m_wv, wimg, out);
}